// Round 4
// baseline (361.367 us; speedup 1.0000x reference)
//
#include <hip/hip_runtime.h>
#include <hip/hip_bf16.h>

// B=128, S=256, E=768, C=4; M = B*S = 32768.
// 4 launches:
//  prep:  segB=bf16(segments) | W1t=bf16(W1[768:].T) | W2t=bf16(W2.T) | qW1=questions@W1[:768]+b1
//  K2:    H1b[32768,768]bf16 = gelu(segB @ W1t^T + qW1[bag])     (MFMA 32x32x16, BK=64)
//  K3:    H2b[32768,384]bf16 = gelu(H1b @ W2t^T + b2)            (MFMA 32x32x16, BK=64)
//  head:  out[128,4] = aggregate(softmax(H2b @ W3 + b3))         (fused K4+K5)

typedef __attribute__((ext_vector_type(8))) short short8;
typedef __attribute__((ext_vector_type(8))) unsigned short ushort8;
typedef __attribute__((ext_vector_type(4))) float f32x4;
typedef __attribute__((ext_vector_type(16))) float f32x16;

__device__ __forceinline__ unsigned short f2bf(float f) {
    union { float f; unsigned int u; } c; c.f = f;
    unsigned int u = c.u;
    unsigned int r = (u + 0x7FFFu + ((u >> 16) & 1u)) >> 16;  // RNE
    return (unsigned short)r;
}
__device__ __forceinline__ float bf2f(unsigned short u) {
    union { unsigned int u; float f; } c; c.u = ((unsigned int)u) << 16;
    return c.f;
}
// tanh-form gelu via HW exp/rcp
__device__ __forceinline__ float gelu_fast(float x) {
    float x2 = x * x;
    float y2 = 1.5957691216057308f * (x + 0.044715f * x2 * x);
    float e = __expf(y2);
    float t = 1.0f - 2.0f * __builtin_amdgcn_rcpf(e + 1.0f);
    return 0.5f * x * (1.0f + t);
}

typedef const __attribute__((address_space(1))) void* gas_t;
typedef __attribute__((address_space(3))) void* las_t;
__device__ __forceinline__ void g2l16(const void* g, void* l) {
    __builtin_amdgcn_global_load_lds((gas_t)g, (las_t)l, 16, 0, 0);
}

// ---------------- fused prep kernel ----------------
// blocks [0,12288): conv segments->segB (bf16x8)
// blocks [12288,12432): transpose W1seg -> W1t   (12x12)
// blocks [12432,12504): transpose W2    -> W2t   (6x12)
// blocks [12504,12528): qW1 = questions @ W1[:768] + b1  (fp32 gemm, 12x2)
#define PREP_CONV 12288
#define PREP_TR1  12432
#define PREP_TR2  12504
#define PREP_END  12528

__global__ __launch_bounds__(256) void prep_kernel(
    const float* __restrict__ segments, unsigned short* __restrict__ segB,
    const float* __restrict__ W1, unsigned short* __restrict__ W1t,
    const float* __restrict__ W2, unsigned short* __restrict__ W2t,
    const float* __restrict__ questions, const float* __restrict__ b1,
    float* __restrict__ qW1)
{
    __shared__ __align__(16) char sh[16640];
    const int bid = blockIdx.x, tid = threadIdx.x;

    if (bid < PREP_CONV) {
        long i = (long)bid * 256 + tid;
        const float4* in = (const float4*)segments;
        float4 a = in[2 * i], b = in[2 * i + 1];
        ushort8 o;
        o[0] = f2bf(a.x); o[1] = f2bf(a.y); o[2] = f2bf(a.z); o[3] = f2bf(a.w);
        o[4] = f2bf(b.x); o[5] = f2bf(b.y); o[6] = f2bf(b.z); o[7] = f2bf(b.w);
        *(ushort8*)(segB + i * 8) = o;
        return;
    }

    if (bid < PREP_TR2) {
        // transpose in[R,C] -> out[C,R] (bf16)
        const float* in; unsigned short* outp; int R, C, bx, by;
        if (bid < PREP_TR1) {
            int idx = bid - PREP_CONV; bx = idx % 12; by = idx / 12;
            in = W1 + 768 * 768; outp = W1t; R = 768; C = 768;
        } else {
            int idx = bid - PREP_TR1; bx = idx % 6; by = idx / 6;
            in = W2; outp = W2t; R = 768; C = 384;
        }
        float (*t)[65] = (float(*)[65])sh;
        int r0 = by * 64, c0 = bx * 64;
        int tx = tid & 63, ty = tid >> 6;
        #pragma unroll
        for (int p = 0; p < 16; p++) {
            int row = ty * 16 + p;
            t[row][tx] = in[(size_t)(r0 + row) * C + c0 + tx];
        }
        __syncthreads();
        #pragma unroll
        for (int p = 0; p < 16; p++) {
            int orow = ty * 16 + p;
            outp[(size_t)(c0 + orow) * R + r0 + tx] = f2bf(t[tx][orow]);
        }
        return;
    }

    // qW1 fp32 gemm: M=128,N=768,K=768, 64x64 tiles
    {
        int idx = bid - PREP_TR2;
        int n0 = (idx % 12) * 64, m0 = (idx / 12) * 64;
        float (*As)[64] = (float(*)[64])sh;            // [16][64]
        float (*Bs)[64] = (float(*)[64])(sh + 4096);   // [16][64]
        const int tn = tid & 15, tm = tid >> 4;
        float acc[4][4] = {};
        const int la_m = tid >> 2;
        const int la_k = (tid & 3) << 2;
        const int lb_k = tid >> 4;
        const int lb_n = (tid & 15) << 2;
        const float* Aptr = questions + (size_t)(m0 + la_m) * 768 + la_k;
        const float* Bptr = W1 + (size_t)lb_k * 768 + n0 + lb_n;
        for (int k0 = 0; k0 < 768; k0 += 16) {
            float4 av = *(const float4*)(Aptr + k0);
            float4 bv = *(const float4*)(Bptr + (size_t)k0 * 768);
            As[la_k + 0][la_m] = av.x;
            As[la_k + 1][la_m] = av.y;
            As[la_k + 2][la_m] = av.z;
            As[la_k + 3][la_m] = av.w;
            *(float4*)&Bs[lb_k][lb_n] = bv;
            __syncthreads();
            #pragma unroll
            for (int k = 0; k < 16; k++) {
                float4 a = *(const float4*)&As[k][tm << 2];
                float4 b = *(const float4*)&Bs[k][tn << 2];
                float ar[4] = {a.x, a.y, a.z, a.w};
                float br[4] = {b.x, b.y, b.z, b.w};
                #pragma unroll
                for (int i = 0; i < 4; i++)
                    #pragma unroll
                    for (int j = 0; j < 4; j++)
                        acc[i][j] += ar[i] * br[j];
            }
            __syncthreads();
        }
        #pragma unroll
        for (int i = 0; i < 4; i++) {
            int row = m0 + (tm << 2) + i;
            int colBase = n0 + (tn << 2);
            float vals[4];
            #pragma unroll
            for (int j = 0; j < 4; j++)
                vals[j] = acc[i][j] + b1[colBase + j];
            *(float4*)&qW1[(size_t)row * 768 + colBase] =
                make_float4(vals[0], vals[1], vals[2], vals[3]);
        }
    }
}

// ---------------- bf16 MFMA GEMM, B^T input, 32x32x16, BK=64 ----------------
__global__ __launch_bounds__(256) void mfma_gemm_bt(
    const unsigned short* __restrict__ A,    // [M,K] bf16
    const unsigned short* __restrict__ Bt,   // [N,K] bf16
    const float* __restrict__ bias,          // [N] or null
    const float* __restrict__ rowAdd,        // [M/256, N] or null
    unsigned short* __restrict__ Cout,       // [M,N] bf16
    int M, int N, int K, int applyGelu)
{
    // 32 KB: staging As(16K)+Bs(16K); epilogue reuses all 32K as C-tile.
    __shared__ __align__(16) unsigned short smem[128 * 128];
    unsigned short* As = smem;             // [128 rows][64 k]
    unsigned short* Bs = smem + 8192;      // [128 n][64 k]
    const int tid = threadIdx.x;
    const int wave = tid >> 6, lane = tid & 63;
    const int m0 = blockIdx.y * 128, n0 = blockIdx.x * 128;
    const int wm = (wave & 1) * 64, wn = (wave >> 1) * 64;

    f32x16 acc[2][2] = {};

    // staging: thread -> (row = tid>>3 + 32*round, col = (tid&7)*8)
    const unsigned short* Ag = A + (size_t)(m0 + (tid >> 3)) * K + (tid & 7) * 8;
    const unsigned short* Bg = Bt + (size_t)(n0 + (tid >> 3)) * K + (tid & 7) * 8;
    unsigned short* Al = As + tid * 8;
    unsigned short* Bl = Bs + tid * 8;

    const int fm = lane & 31, fq = lane >> 5;   // frag row/col, k-half select

    for (int k0 = 0; k0 < K; k0 += 64) {
        #pragma unroll
        for (int r = 0; r < 4; r++) {
            g2l16(Ag + k0 + (size_t)(32 * r) * K, Al + r * 2048);
            g2l16(Bg + k0 + (size_t)(32 * r) * K, Bl + r * 2048);
        }
        __syncthreads();

        short8 af[2][4], bfr[2][4];
        #pragma unroll
        for (int i = 0; i < 2; i++)
            #pragma unroll
            for (int kh = 0; kh < 4; kh++)
                af[i][kh] = *(const short8*)&As[(wm + i * 32 + fm) * 64 + kh * 16 + fq * 8];
        #pragma unroll
        for (int j = 0; j < 2; j++)
            #pragma unroll
            for (int kh = 0; kh < 4; kh++)
                bfr[j][kh] = *(const short8*)&Bs[(wn + j * 32 + fm) * 64 + kh * 16 + fq * 8];
        #pragma unroll
        for (int kh = 0; kh < 4; kh++)
            #pragma unroll
            for (int i = 0; i < 2; i++)
                #pragma unroll
                for (int j = 0; j < 2; j++)
                    acc[i][j] = __builtin_amdgcn_mfma_f32_32x32x16_bf16(
                        af[i][kh], bfr[j][kh], acc[i][j], 0, 0, 0);
        __syncthreads();
    }

    // Epilogue: 32x32 C/D layout: col=lane&31, row=(reg&3)+8*(reg>>2)+4*(lane>>5)
    const float* radd = rowAdd ? (rowAdd + (size_t)(m0 >> 8) * N) : nullptr;
    #pragma unroll
    for (int j = 0; j < 2; j++) {
        int coll = wn + j * 32 + fm;
        int col = n0 + coll;
        float add = (bias ? bias[col] : 0.0f) + (radd ? radd[col] : 0.0f);
        #pragma unroll
        for (int i = 0; i < 2; i++) {
            int rbase = wm + i * 32 + 4 * fq;
            #pragma unroll
            for (int reg = 0; reg < 16; reg++) {
                int rowl = rbase + (reg & 3) + 8 * (reg >> 2);
                float v = acc[i][j][reg] + add;
                if (applyGelu) v = gelu_fast(v);
                smem[rowl * 128 + coll] = f2bf(v);
            }
        }
    }
    __syncthreads();
    #pragma unroll
    for (int it = 0; it < 8; it++) {
        int idx = it * 256 + tid;
        int r = idx >> 4, cc = (idx & 15) * 8;
        *(ushort8*)&Cout[(size_t)(m0 + r) * N + n0 + cc] =
            *(const ushort8*)&smem[r * 128 + cc];
    }
}

// ---------------- fused head: layer3 + softmax + aggregation ----------------
__device__ __forceinline__ float4 f4mul(float4 a, float4 b) {
    return make_float4(a.x * b.x, a.y * b.y, a.z * b.z, a.w * b.w);
}
__device__ float4 scan_prod(float4 v, float4* buf, int tid) {
    __syncthreads();
    buf[tid] = v;
    __syncthreads();
    #pragma unroll
    for (int off = 1; off < 256; off <<= 1) {
        float4 o = (tid >= off) ? buf[tid - off] : make_float4(1.f, 1.f, 1.f, 1.f);
        __syncthreads();
        v = f4mul(v, o);
        buf[tid] = v;
        __syncthreads();
    }
    return v;
}

__global__ __launch_bounds__(256) void head_kernel(
    const unsigned short* __restrict__ H2, const float* __restrict__ W3,
    const float* __restrict__ b3, const int* __restrict__ nseg,
    float* __restrict__ out)
{
    __shared__ float4 buf[256];
    __shared__ float4 w3s[384];   // w3s[k] = W3[k][0..3]
    const int b = blockIdx.x, tid = threadIdx.x;
    for (int i = tid; i < 384; i += 256) w3s[i] = ((const float4*)W3)[i];
    __syncthreads();

    // layer 3: each thread owns one row (segment)
    const unsigned short* hrow = H2 + (size_t)(b * 256 + tid) * 384;
    float4 acc = make_float4(b3[0], b3[1], b3[2], b3[3]);
    #pragma unroll
    for (int kk = 0; kk < 48; kk++) {
        ushort8 u = *(const ushort8*)(hrow + kk * 8);
        #pragma unroll
        for (int j = 0; j < 8; j++) {
            float h = bf2f(u[j]);
            float4 w = w3s[kk * 8 + j];
            acc.x += h * w.x; acc.y += h * w.y; acc.z += h * w.z; acc.w += h * w.w;
        }
    }
    // softmax (per-thread, 4-wide)
    float m = fmaxf(fmaxf(acc.x, acc.y), fmaxf(acc.z, acc.w));
    float e0 = __expf(acc.x - m), e1 = __expf(acc.y - m),
          e2 = __expf(acc.z - m), e3 = __expf(acc.w - m);
    float inv = 1.0f / (e0 + e1 + e2 + e3);
    float4 p = make_float4(e0 * inv, e1 * inv, e2 * inv, e3 * inv);

    // aggregation
    const int n = nseg[b];
    const float4 ones = make_float4(1.f, 1.f, 1.f, 1.f);
    bool msk = tid < n;
    float s1 = p.x, s2 = s1 + p.y, s3 = s2 + p.z;
    float4 sm = msk ? make_float4(0.f, s1, s2, s3) : ones;

    scan_prod(sm, buf, tid);
    float4 pfx = (tid > 0) ? buf[tid - 1] : ones;
    __syncthreads();

    buf[255 - tid] = sm;
    __syncthreads();
    float4 rsm = buf[tid];
    scan_prod(rsm, buf, tid);
    float4 sfx = (tid < 255) ? buf[254 - tid] : ones;

    float4 L = f4mul(pfx, sfx);
    float4 cpL = scan_prod(L, buf, tid);

    float4 term = msk ? f4mul(p, cpL) : make_float4(0.f, 0.f, 0.f, 0.f);
    float4 pm = msk ? p : ones;

    __syncthreads();
    buf[tid] = term;
    __syncthreads();
    for (int off = 128; off > 0; off >>= 1) {
        if (tid < off) {
            float4 a = buf[tid], c = buf[tid + off];
            buf[tid] = make_float4(a.x + c.x, a.y + c.y, a.z + c.z, a.w + c.w);
        }
        __syncthreads();
    }
    float4 sum_t = buf[0];
    __syncthreads();

    buf[tid] = pm;
    __syncthreads();
    for (int off = 128; off > 0; off >>= 1) {
        if (tid < off) buf[tid] = f4mul(buf[tid], buf[tid + off]);
        __syncthreads();
    }
    if (tid == 0) {
        float4 pr = buf[0];
        ((float4*)out)[b] = make_float4(0.25f * sum_t.x + pr.x,
                                        0.25f * sum_t.y + pr.y,
                                        0.25f * sum_t.z + pr.z,
                                        0.25f * sum_t.w + pr.w);
    }
}

extern "C" void kernel_launch(void* const* d_in, const int* in_sizes, int n_in,
                              void* d_out, int out_size, void* d_ws, size_t ws_size,
                              hipStream_t stream) {
    (void)in_sizes; (void)n_in; (void)out_size; (void)ws_size;
    const float* questions = (const float*)d_in[0];
    const float* segments  = (const float*)d_in[1];
    const float* W1 = (const float*)d_in[2];
    const float* b1 = (const float*)d_in[3];
    const float* W2 = (const float*)d_in[4];
    const float* b2 = (const float*)d_in[5];
    const float* W3 = (const float*)d_in[6];
    const float* b3 = (const float*)d_in[7];
    const int*  nseg = (const int*)d_in[8];
    float* out = (float*)d_out;

    char* w = (char*)d_ws;
    float* qW1 = (float*)w;            w += (size_t)128 * 768 * 4;
    unsigned short* W1t = (unsigned short*)w; w += (size_t)768 * 768 * 2;
    unsigned short* W2t = (unsigned short*)w; w += (size_t)384 * 768 * 2;
    unsigned short* segB = (unsigned short*)w; w += (size_t)32768 * 768 * 2;
    unsigned short* H1b  = (unsigned short*)w; w += (size_t)32768 * 768 * 2;
    unsigned short* H2b  = (unsigned short*)w; w += (size_t)32768 * 384 * 2;

    prep_kernel<<<PREP_END, 256, 0, stream>>>(
        segments, segB, W1, W1t, W2, W2t, questions, b1, qW1);
    mfma_gemm_bt<<<dim3(6, 256), 256, 0, stream>>>(
        segB, W1t, nullptr, qW1, H1b, 32768, 768, 768, 1);
    mfma_gemm_bt<<<dim3(3, 256), 256, 0, stream>>>(
        H1b, W2t, b2, nullptr, H2b, 32768, 384, 768, 1);
    head_kernel<<<128, 256, 0, stream>>>(H2b, W3, b3, nseg, out);
}

// Round 5
// 324.517 us; speedup vs baseline: 1.1136x; 1.1136x over previous
//
#include <hip/hip_runtime.h>
#include <hip/hip_bf16.h>

// B=128, S=256, E=768, C=4; M = B*S = 32768.
// 4 launches:
//  prep:  segB=bf16(segments) | W1t=bf16(W1[768:].T) | W2t=bf16(W2.T) | qW1=questions@W1[:768]+b1
//  K2:    H1b[32768,768]bf16 = gelu(segB @ W1t^T + qW1[bag])     (MFMA 32x32x16, BK=64, swizzled LDS)
//  K3:    H2b[32768,384]bf16 = gelu(H1b @ W2t^T + b2)
//  head:  out[128,4] = aggregate(softmax(H2b @ W3 + b3))

typedef __attribute__((ext_vector_type(8))) short short8;
typedef __attribute__((ext_vector_type(8))) unsigned short ushort8;
typedef __attribute__((ext_vector_type(4))) float f32x4;
typedef __attribute__((ext_vector_type(16))) float f32x16;

__device__ __forceinline__ unsigned short f2bf(float f) {
    union { float f; unsigned int u; } c; c.f = f;
    unsigned int u = c.u;
    unsigned int r = (u + 0x7FFFu + ((u >> 16) & 1u)) >> 16;  // RNE
    return (unsigned short)r;
}
__device__ __forceinline__ float bf2f(unsigned short u) {
    union { unsigned int u; float f; } c; c.u = ((unsigned int)u) << 16;
    return c.f;
}
__device__ __forceinline__ float gelu_fast(float x) {
    float x2 = x * x;
    float y2 = 1.5957691216057308f * (x + 0.044715f * x2 * x);
    float e = __expf(y2);
    float t = 1.0f - 2.0f * __builtin_amdgcn_rcpf(e + 1.0f);
    return 0.5f * x * (1.0f + t);
}

typedef const __attribute__((address_space(1))) void* gas_t;
typedef __attribute__((address_space(3))) void* las_t;
__device__ __forceinline__ void g2l16(const void* g, void* l) {
    __builtin_amdgcn_global_load_lds((gas_t)g, (las_t)l, 16, 0, 0);
}

// ---------------- fused prep kernel ----------------
#define PREP_CONV 12288
#define PREP_TR1  12432
#define PREP_TR2  12504
#define PREP_END  12528

__global__ __launch_bounds__(256) void prep_kernel(
    const float* __restrict__ segments, unsigned short* __restrict__ segB,
    const float* __restrict__ W1, unsigned short* __restrict__ W1t,
    const float* __restrict__ W2, unsigned short* __restrict__ W2t,
    const float* __restrict__ questions, const float* __restrict__ b1,
    float* __restrict__ qW1)
{
    __shared__ __align__(16) char sh[16640];
    const int bid = blockIdx.x, tid = threadIdx.x;

    if (bid < PREP_CONV) {
        long i = (long)bid * 256 + tid;
        const float4* in = (const float4*)segments;
        float4 a = in[2 * i], b = in[2 * i + 1];
        ushort8 o;
        o[0] = f2bf(a.x); o[1] = f2bf(a.y); o[2] = f2bf(a.z); o[3] = f2bf(a.w);
        o[4] = f2bf(b.x); o[5] = f2bf(b.y); o[6] = f2bf(b.z); o[7] = f2bf(b.w);
        *(ushort8*)(segB + i * 8) = o;
        return;
    }

    if (bid < PREP_TR2) {
        const float* in; unsigned short* outp; int R, C, bx, by;
        if (bid < PREP_TR1) {
            int idx = bid - PREP_CONV; bx = idx % 12; by = idx / 12;
            in = W1 + 768 * 768; outp = W1t; R = 768; C = 768;
        } else {
            int idx = bid - PREP_TR1; bx = idx % 6; by = idx / 6;
            in = W2; outp = W2t; R = 768; C = 384;
        }
        float (*t)[65] = (float(*)[65])sh;
        int r0 = by * 64, c0 = bx * 64;
        int tx = tid & 63, ty = tid >> 6;
        #pragma unroll
        for (int p = 0; p < 16; p++) {
            int row = ty * 16 + p;
            t[row][tx] = in[(size_t)(r0 + row) * C + c0 + tx];
        }
        __syncthreads();
        #pragma unroll
        for (int p = 0; p < 16; p++) {
            int orow = ty * 16 + p;
            outp[(size_t)(c0 + orow) * R + r0 + tx] = f2bf(t[tx][orow]);
        }
        return;
    }

    // qW1 fp32 gemm: M=128,N=768,K=768, 64x64 tiles
    {
        int idx = bid - PREP_TR2;
        int n0 = (idx % 12) * 64, m0 = (idx / 12) * 64;
        float (*As)[64] = (float(*)[64])sh;
        float (*Bs)[64] = (float(*)[64])(sh + 4096);
        const int tn = tid & 15, tm = tid >> 4;
        float acc[4][4] = {};
        const int la_m = tid >> 2;
        const int la_k = (tid & 3) << 2;
        const int lb_k = tid >> 4;
        const int lb_n = (tid & 15) << 2;
        const float* Aptr = questions + (size_t)(m0 + la_m) * 768 + la_k;
        const float* Bptr = W1 + (size_t)lb_k * 768 + n0 + lb_n;
        for (int k0 = 0; k0 < 768; k0 += 16) {
            float4 av = *(const float4*)(Aptr + k0);
            float4 bv = *(const float4*)(Bptr + (size_t)k0 * 768);
            As[la_k + 0][la_m] = av.x;
            As[la_k + 1][la_m] = av.y;
            As[la_k + 2][la_m] = av.z;
            As[la_k + 3][la_m] = av.w;
            *(float4*)&Bs[lb_k][lb_n] = bv;
            __syncthreads();
            #pragma unroll
            for (int k = 0; k < 16; k++) {
                float4 a = *(const float4*)&As[k][tm << 2];
                float4 b = *(const float4*)&Bs[k][tn << 2];
                float ar[4] = {a.x, a.y, a.z, a.w};
                float br[4] = {b.x, b.y, b.z, b.w};
                #pragma unroll
                for (int i = 0; i < 4; i++)
                    #pragma unroll
                    for (int j = 0; j < 4; j++)
                        acc[i][j] += ar[i] * br[j];
            }
            __syncthreads();
        }
        #pragma unroll
        for (int i = 0; i < 4; i++) {
            int row = m0 + (tm << 2) + i;
            int colBase = n0 + (tn << 2);
            float vals[4];
            #pragma unroll
            for (int j = 0; j < 4; j++)
                vals[j] = acc[i][j] + b1[colBase + j];
            *(float4*)&qW1[(size_t)row * 768 + colBase] =
                make_float4(vals[0], vals[1], vals[2], vals[3]);
        }
    }
}

// ---------------- bf16 MFMA GEMM, B^T input, 32x32x16, BK=64, XOR-swizzled LDS ----
// LDS[row][p] holds global chunk (p ^ (row&7)) of that row (chunks are 8 bf16 = 16 B).
// Staging source swizzle (global addr per lane) keeps global_load_lds's
// wave-uniform-base + lane*16 dest contiguous; frag reads XOR back.
__global__ __launch_bounds__(256) void mfma_gemm_bt(
    const unsigned short* __restrict__ A,    // [M,K] bf16
    const unsigned short* __restrict__ Bt,   // [N,K] bf16
    const float* __restrict__ bias,          // [N] or null
    const float* __restrict__ rowAdd,        // [M/256, N] or null
    unsigned short* __restrict__ Cout,       // [M,N] bf16
    int M, int N, int K, int applyGelu)
{
    __shared__ __align__(16) unsigned short smem[128 * 128];
    unsigned short* As = smem;             // [128 rows][64 k] (swizzled)
    unsigned short* Bs = smem + 8192;      // [128 n][64 k]   (swizzled)
    const int tid = threadIdx.x;
    const int wave = tid >> 6, lane = tid & 63;
    const int m0 = blockIdx.y * 128, n0 = blockIdx.x * 128;
    const int wm = (wave & 1) * 64, wn = (wave >> 1) * 64;

    f32x16 acc[2][2] = {};

    // staging: thread tid -> LDS row (tid>>3)+32r, position chunk tid&7;
    // source chunk = (tid&7) ^ (row&7); (row&7) invariant across rounds r.
    const int srow = tid >> 3;
    const int schunk = (tid & 7) ^ (srow & 7);
    const unsigned short* Ag = A + (size_t)(m0 + srow) * K + schunk * 8;
    const unsigned short* Bg = Bt + (size_t)(n0 + srow) * K + schunk * 8;
    unsigned short* Al = As + tid * 8;
    unsigned short* Bl = Bs + tid * 8;

    const int fm = lane & 31, fq = lane >> 5;
    const int fs = fm & 7;   // swizzle key for frag reads

    for (int k0 = 0; k0 < K; k0 += 64) {
        #pragma unroll
        for (int r = 0; r < 4; r++) {
            g2l16(Ag + k0 + (size_t)(32 * r) * K, Al + r * 2048);
            g2l16(Bg + k0 + (size_t)(32 * r) * K, Bl + r * 2048);
        }
        __syncthreads();

        short8 af[2][4], bfr[2][4];
        #pragma unroll
        for (int i = 0; i < 2; i++)
            #pragma unroll
            for (int kh = 0; kh < 4; kh++)
                af[i][kh] = *(const short8*)
                    &As[(wm + i * 32 + fm) * 64 + (((kh << 1) | fq) ^ fs) * 8];
        #pragma unroll
        for (int j = 0; j < 2; j++)
            #pragma unroll
            for (int kh = 0; kh < 4; kh++)
                bfr[j][kh] = *(const short8*)
                    &Bs[(wn + j * 32 + fm) * 64 + (((kh << 1) | fq) ^ fs) * 8];
        #pragma unroll
        for (int kh = 0; kh < 4; kh++)
            #pragma unroll
            for (int i = 0; i < 2; i++)
                #pragma unroll
                for (int j = 0; j < 2; j++)
                    acc[i][j] = __builtin_amdgcn_mfma_f32_32x32x16_bf16(
                        af[i][kh], bfr[j][kh], acc[i][j], 0, 0, 0);
        __syncthreads();
    }

    // Epilogue: 32x32 C/D layout: col=lane&31, row=(reg&3)+8*(reg>>2)+4*(lane>>5)
    const float* radd = rowAdd ? (rowAdd + (size_t)(m0 >> 8) * N) : nullptr;
    #pragma unroll
    for (int j = 0; j < 2; j++) {
        int coll = wn + j * 32 + fm;
        int col = n0 + coll;
        float add = (bias ? bias[col] : 0.0f) + (radd ? radd[col] : 0.0f);
        #pragma unroll
        for (int i = 0; i < 2; i++) {
            int rbase = wm + i * 32 + 4 * fq;
            #pragma unroll
            for (int reg = 0; reg < 16; reg++) {
                int rowl = rbase + (reg & 3) + 8 * (reg >> 2);
                float v = acc[i][j][reg] + add;
                if (applyGelu) v = gelu_fast(v);
                smem[rowl * 128 + coll] = f2bf(v);
            }
        }
    }
    __syncthreads();
    #pragma unroll
    for (int it = 0; it < 8; it++) {
        int idx = it * 256 + tid;
        int r = idx >> 4, cc = (idx & 15) * 8;
        *(ushort8*)&Cout[(size_t)(m0 + r) * N + n0 + cc] =
            *(const ushort8*)&smem[r * 128 + cc];
    }
}

// ---------------- fused head: layer3 + softmax + aggregation ----------------
__device__ __forceinline__ float4 f4mul(float4 a, float4 b) {
    return make_float4(a.x * b.x, a.y * b.y, a.z * b.z, a.w * b.w);
}
__device__ float4 scan_prod(float4 v, float4* buf, int tid) {
    __syncthreads();
    buf[tid] = v;
    __syncthreads();
    #pragma unroll
    for (int off = 1; off < 256; off <<= 1) {
        float4 o = (tid >= off) ? buf[tid - off] : make_float4(1.f, 1.f, 1.f, 1.f);
        __syncthreads();
        v = f4mul(v, o);
        buf[tid] = v;
        __syncthreads();
    }
    return v;
}

__global__ __launch_bounds__(256) void head_kernel(
    const unsigned short* __restrict__ H2, const float* __restrict__ W3,
    const float* __restrict__ b3, const int* __restrict__ nseg,
    float* __restrict__ out)
{
    __shared__ float4 buf[256];
    __shared__ float4 w3s[384];
    const int b = blockIdx.x, tid = threadIdx.x;
    for (int i = tid; i < 384; i += 256) w3s[i] = ((const float4*)W3)[i];
    __syncthreads();

    const unsigned short* hrow = H2 + (size_t)(b * 256 + tid) * 384;
    float4 acc = make_float4(b3[0], b3[1], b3[2], b3[3]);
    #pragma unroll
    for (int kk = 0; kk < 48; kk++) {
        ushort8 u = *(const ushort8*)(hrow + kk * 8);
        #pragma unroll
        for (int j = 0; j < 8; j++) {
            float h = bf2f(u[j]);
            float4 w = w3s[kk * 8 + j];
            acc.x += h * w.x; acc.y += h * w.y; acc.z += h * w.z; acc.w += h * w.w;
        }
    }
    float m = fmaxf(fmaxf(acc.x, acc.y), fmaxf(acc.z, acc.w));
    float e0 = __expf(acc.x - m), e1 = __expf(acc.y - m),
          e2 = __expf(acc.z - m), e3 = __expf(acc.w - m);
    float inv = 1.0f / (e0 + e1 + e2 + e3);
    float4 p = make_float4(e0 * inv, e1 * inv, e2 * inv, e3 * inv);

    const int n = nseg[b];
    const float4 ones = make_float4(1.f, 1.f, 1.f, 1.f);
    bool msk = tid < n;
    float s1 = p.x, s2 = s1 + p.y, s3 = s2 + p.z;
    float4 sm = msk ? make_float4(0.f, s1, s2, s3) : ones;

    scan_prod(sm, buf, tid);
    float4 pfx = (tid > 0) ? buf[tid - 1] : ones;
    __syncthreads();

    buf[255 - tid] = sm;
    __syncthreads();
    float4 rsm = buf[tid];
    scan_prod(rsm, buf, tid);
    float4 sfx = (tid < 255) ? buf[254 - tid] : ones;

    float4 L = f4mul(pfx, sfx);
    float4 cpL = scan_prod(L, buf, tid);

    float4 term = msk ? f4mul(p, cpL) : make_float4(0.f, 0.f, 0.f, 0.f);
    float4 pm = msk ? p : ones;

    __syncthreads();
    buf[tid] = term;
    __syncthreads();
    for (int off = 128; off > 0; off >>= 1) {
        if (tid < off) {
            float4 a = buf[tid], c = buf[tid + off];
            buf[tid] = make_float4(a.x + c.x, a.y + c.y, a.z + c.z, a.w + c.w);
        }
        __syncthreads();
    }
    float4 sum_t = buf[0];
    __syncthreads();

    buf[tid] = pm;
    __syncthreads();
    for (int off = 128; off > 0; off >>= 1) {
        if (tid < off) buf[tid] = f4mul(buf[tid], buf[tid + off]);
        __syncthreads();
    }
    if (tid == 0) {
        float4 pr = buf[0];
        ((float4*)out)[b] = make_float4(0.25f * sum_t.x + pr.x,
                                        0.25f * sum_t.y + pr.y,
                                        0.25f * sum_t.z + pr.z,
                                        0.25f * sum_t.w + pr.w);
    }
}

extern "C" void kernel_launch(void* const* d_in, const int* in_sizes, int n_in,
                              void* d_out, int out_size, void* d_ws, size_t ws_size,
                              hipStream_t stream) {
    (void)in_sizes; (void)n_in; (void)out_size; (void)ws_size;
    const float* questions = (const float*)d_in[0];
    const float* segments  = (const float*)d_in[1];
    const float* W1 = (const float*)d_in[2];
    const float* b1 = (const float*)d_in[3];
    const float* W2 = (const float*)d_in[4];
    const float* b2 = (const float*)d_in[5];
    const float* W3 = (const float*)d_in[6];
    const float* b3 = (const float*)d_in[7];
    const int*  nseg = (const int*)d_in[8];
    float* out = (float*)d_out;

    char* w = (char*)d_ws;
    float* qW1 = (float*)w;            w += (size_t)128 * 768 * 4;
    unsigned short* W1t = (unsigned short*)w; w += (size_t)768 * 768 * 2;
    unsigned short* W2t = (unsigned short*)w; w += (size_t)384 * 768 * 2;
    unsigned short* segB = (unsigned short*)w; w += (size_t)32768 * 768 * 2;
    unsigned short* H1b  = (unsigned short*)w; w += (size_t)32768 * 768 * 2;
    unsigned short* H2b  = (unsigned short*)w; w += (size_t)32768 * 384 * 2;

    prep_kernel<<<PREP_END, 256, 0, stream>>>(
        segments, segB, W1, W1t, W2, W2t, questions, b1, qW1);
    mfma_gemm_bt<<<dim3(6, 256), 256, 0, stream>>>(
        segB, W1t, nullptr, qW1, H1b, 32768, 768, 768, 1);
    mfma_gemm_bt<<<dim3(3, 256), 256, 0, stream>>>(
        H1b, W2t, b2, nullptr, H2b, 32768, 384, 768, 1);
    head_kernel<<<128, 256, 0, stream>>>(H2b, W3, b3, nseg, out);
}

// Round 6
// 283.638 us; speedup vs baseline: 1.2740x; 1.1441x over previous
//
#include <hip/hip_runtime.h>
#include <hip/hip_bf16.h>

// B=128, S=256, E=768, C=4; M = B*S = 32768.
// 4 launches:
//  prep:  qW1 partials (K-split x4, fp32) | W1t/W2t transposes | segB=bf16(segments)
//         (qW1/tr blocks FIRST so they overlap the conv stream — r5 showed a
//          ~55us straggler tail when the 24 qW1 blocks dispatched last)
//  K2:    H1b[32768,768]bf16 = gelu(segB @ W1t^T + b1 + sum_s qW1p[s][bag])  (MFMA 32x32x16)
//  K3:    H2b[32768,384]bf16 = gelu(H1b @ W2t^T + b2)
//  head:  out[128,4] = aggregate(softmax(H2b @ W3 + b3))

typedef __attribute__((ext_vector_type(8))) short short8;
typedef __attribute__((ext_vector_type(8))) unsigned short ushort8;
typedef __attribute__((ext_vector_type(4))) float f32x4;
typedef __attribute__((ext_vector_type(16))) float f32x16;

__device__ __forceinline__ unsigned short f2bf(float f) {
    union { float f; unsigned int u; } c; c.f = f;
    unsigned int u = c.u;
    unsigned int r = (u + 0x7FFFu + ((u >> 16) & 1u)) >> 16;  // RNE
    return (unsigned short)r;
}
__device__ __forceinline__ float bf2f(unsigned short u) {
    union { unsigned int u; float f; } c; c.u = ((unsigned int)u) << 16;
    return c.f;
}
__device__ __forceinline__ float gelu_fast(float x) {
    float x2 = x * x;
    float y2 = 1.5957691216057308f * (x + 0.044715f * x2 * x);
    float e = __expf(y2);
    float t = 1.0f - 2.0f * __builtin_amdgcn_rcpf(e + 1.0f);
    return 0.5f * x * (1.0f + t);
}

typedef const __attribute__((address_space(1))) void* gas_t;
typedef __attribute__((address_space(3))) void* las_t;
__device__ __forceinline__ void g2l16(const void* g, void* l) {
    __builtin_amdgcn_global_load_lds((gas_t)g, (las_t)l, 16, 0, 0);
}

// ---------------- fused prep kernel ----------------
// blocks [0,96):        qW1 partials: 4 K-slices x (12 n-tiles x 2 m-tiles)
// blocks [96,240):      transpose W1[768:] -> W1t  (12x12 tiles)
// blocks [240,312):     transpose W2 -> W2t        (6x12 tiles)
// blocks [312,12600):   conv segments -> segB bf16
#define PREP_Q    96
#define PREP_TR1E 240
#define PREP_TR2E 312
#define PREP_END  12600

__global__ __launch_bounds__(256) void prep_kernel(
    const float* __restrict__ segments, unsigned short* __restrict__ segB,
    const float* __restrict__ W1, unsigned short* __restrict__ W1t,
    const float* __restrict__ W2, unsigned short* __restrict__ W2t,
    const float* __restrict__ questions, float* __restrict__ qW1p)
{
    __shared__ __align__(16) char sh[16640];
    const int bid = blockIdx.x, tid = threadIdx.x;

    if (bid < PREP_Q) {
        // qW1 partial: slice s, 64x64 tile. K slice = [s*192, s*192+192)
        const int s = bid / 24, rem = bid % 24;
        const int n0 = (rem % 12) * 64, m0 = (rem / 12) * 64;
        float (*As)[64] = (float(*)[64])sh;
        float (*Bs)[64] = (float(*)[64])(sh + 4096);
        const int tn = tid & 15, tm = tid >> 4;
        float acc[4][4] = {};
        const int la_m = tid >> 2;
        const int la_k = (tid & 3) << 2;
        const int lb_k = tid >> 4;
        const int lb_n = (tid & 15) << 2;
        const float* Aptr = questions + (size_t)(m0 + la_m) * 768 + la_k;
        const float* Bptr = W1 + (size_t)lb_k * 768 + n0 + lb_n;
        const int kbeg = s * 192, kend = kbeg + 192;
        for (int k0 = kbeg; k0 < kend; k0 += 16) {
            float4 av = *(const float4*)(Aptr + k0);
            float4 bv = *(const float4*)(Bptr + (size_t)k0 * 768);
            As[la_k + 0][la_m] = av.x;
            As[la_k + 1][la_m] = av.y;
            As[la_k + 2][la_m] = av.z;
            As[la_k + 3][la_m] = av.w;
            *(float4*)&Bs[lb_k][lb_n] = bv;
            __syncthreads();
            #pragma unroll
            for (int k = 0; k < 16; k++) {
                float4 a = *(const float4*)&As[k][tm << 2];
                float4 b = *(const float4*)&Bs[k][tn << 2];
                float ar[4] = {a.x, a.y, a.z, a.w};
                float br[4] = {b.x, b.y, b.z, b.w};
                #pragma unroll
                for (int i = 0; i < 4; i++)
                    #pragma unroll
                    for (int j = 0; j < 4; j++)
                        acc[i][j] += ar[i] * br[j];
            }
            __syncthreads();
        }
        float* outp = qW1p + (size_t)s * 128 * 768;
        #pragma unroll
        for (int i = 0; i < 4; i++) {
            int row = m0 + (tm << 2) + i;
            int colBase = n0 + (tn << 2);
            *(float4*)&outp[(size_t)row * 768 + colBase] =
                make_float4(acc[i][0], acc[i][1], acc[i][2], acc[i][3]);
        }
        return;
    }

    if (bid < PREP_TR2E) {
        const float* in; unsigned short* outp; int R, C, bx, by;
        if (bid < PREP_TR1E) {
            int idx = bid - PREP_Q; bx = idx % 12; by = idx / 12;
            in = W1 + 768 * 768; outp = W1t; R = 768; C = 768;
        } else {
            int idx = bid - PREP_TR1E; bx = idx % 6; by = idx / 6;
            in = W2; outp = W2t; R = 768; C = 384;
        }
        float (*t)[65] = (float(*)[65])sh;
        int r0 = by * 64, c0 = bx * 64;
        int tx = tid & 63, ty = tid >> 6;
        #pragma unroll
        for (int p = 0; p < 16; p++) {
            int row = ty * 16 + p;
            t[row][tx] = in[(size_t)(r0 + row) * C + c0 + tx];
        }
        __syncthreads();
        #pragma unroll
        for (int p = 0; p < 16; p++) {
            int orow = ty * 16 + p;
            outp[(size_t)(c0 + orow) * R + r0 + tx] = f2bf(t[tx][orow]);
        }
        return;
    }

    // conv: segments fp32 -> segB bf16 (8 elems/thread)
    {
        long i = (long)(bid - PREP_TR2E) * 256 + tid;
        const float4* in = (const float4*)segments;
        float4 a = in[2 * i], b = in[2 * i + 1];
        ushort8 o;
        o[0] = f2bf(a.x); o[1] = f2bf(a.y); o[2] = f2bf(a.z); o[3] = f2bf(a.w);
        o[4] = f2bf(b.x); o[5] = f2bf(b.y); o[6] = f2bf(b.z); o[7] = f2bf(b.w);
        *(ushort8*)(segB + i * 8) = o;
    }
}

// ---------------- bf16 MFMA GEMM, B^T input, 32x32x16, BK=64, XOR-swizzled LDS ----
// rowAdd: 4 partial slices of [128,768] (stride 128*768), summed per column; or null.
__global__ __launch_bounds__(256) void mfma_gemm_bt(
    const unsigned short* __restrict__ A,    // [M,K] bf16
    const unsigned short* __restrict__ Bt,   // [N,K] bf16
    const float* __restrict__ bias,          // [N] or null
    const float* __restrict__ rowAdd,        // [4][M/256, N] partials or null
    unsigned short* __restrict__ Cout,       // [M,N] bf16
    int M, int N, int K, int applyGelu)
{
    __shared__ __align__(16) unsigned short smem[128 * 128];
    unsigned short* As = smem;             // [128 rows][64 k] (swizzled)
    unsigned short* Bs = smem + 8192;      // [128 n][64 k]   (swizzled)
    const int tid = threadIdx.x;
    const int wave = tid >> 6, lane = tid & 63;
    const int m0 = blockIdx.y * 128, n0 = blockIdx.x * 128;
    const int wm = (wave & 1) * 64, wn = (wave >> 1) * 64;

    f32x16 acc[2][2] = {};

    const int srow = tid >> 3;
    const int schunk = (tid & 7) ^ (srow & 7);
    const unsigned short* Ag = A + (size_t)(m0 + srow) * K + schunk * 8;
    const unsigned short* Bg = Bt + (size_t)(n0 + srow) * K + schunk * 8;
    unsigned short* Al = As + tid * 8;
    unsigned short* Bl = Bs + tid * 8;

    const int fm = lane & 31, fq = lane >> 5;
    const int fs = fm & 7;

    for (int k0 = 0; k0 < K; k0 += 64) {
        #pragma unroll
        for (int r = 0; r < 4; r++) {
            g2l16(Ag + k0 + (size_t)(32 * r) * K, Al + r * 2048);
            g2l16(Bg + k0 + (size_t)(32 * r) * K, Bl + r * 2048);
        }
        __syncthreads();

        short8 af[2][4], bfr[2][4];
        #pragma unroll
        for (int i = 0; i < 2; i++)
            #pragma unroll
            for (int kh = 0; kh < 4; kh++)
                af[i][kh] = *(const short8*)
                    &As[(wm + i * 32 + fm) * 64 + (((kh << 1) | fq) ^ fs) * 8];
        #pragma unroll
        for (int j = 0; j < 2; j++)
            #pragma unroll
            for (int kh = 0; kh < 4; kh++)
                bfr[j][kh] = *(const short8*)
                    &Bs[(wn + j * 32 + fm) * 64 + (((kh << 1) | fq) ^ fs) * 8];
        #pragma unroll
        for (int kh = 0; kh < 4; kh++)
            #pragma unroll
            for (int i = 0; i < 2; i++)
                #pragma unroll
                for (int j = 0; j < 2; j++)
                    acc[i][j] = __builtin_amdgcn_mfma_f32_32x32x16_bf16(
                        af[i][kh], bfr[j][kh], acc[i][j], 0, 0, 0);
        __syncthreads();
    }

    // Epilogue: 32x32 C/D layout: col=lane&31, row=(reg&3)+8*(reg>>2)+4*(lane>>5)
    const float* radd = rowAdd ? (rowAdd + (size_t)(m0 >> 8) * N) : nullptr;
    #pragma unroll
    for (int j = 0; j < 2; j++) {
        int coll = wn + j * 32 + fm;
        int col = n0 + coll;
        float add = bias ? bias[col] : 0.0f;
        if (radd)
            add += radd[col] + radd[col + 98304] +
                   radd[col + 2 * 98304] + radd[col + 3 * 98304];
        #pragma unroll
        for (int i = 0; i < 2; i++) {
            int rbase = wm + i * 32 + 4 * fq;
            #pragma unroll
            for (int reg = 0; reg < 16; reg++) {
                int rowl = rbase + (reg & 3) + 8 * (reg >> 2);
                float v = acc[i][j][reg] + add;
                if (applyGelu) v = gelu_fast(v);
                smem[rowl * 128 + coll] = f2bf(v);
            }
        }
    }
    __syncthreads();
    #pragma unroll
    for (int it = 0; it < 8; it++) {
        int idx = it * 256 + tid;
        int r = idx >> 4, cc = (idx & 15) * 8;
        *(ushort8*)&Cout[(size_t)(m0 + r) * N + n0 + cc] =
            *(const ushort8*)&smem[r * 128 + cc];
    }
}

// ---------------- fused head: layer3 + softmax + aggregation ----------------
__device__ __forceinline__ float4 f4mul(float4 a, float4 b) {
    return make_float4(a.x * b.x, a.y * b.y, a.z * b.z, a.w * b.w);
}
__device__ float4 scan_prod(float4 v, float4* buf, int tid) {
    __syncthreads();
    buf[tid] = v;
    __syncthreads();
    #pragma unroll
    for (int off = 1; off < 256; off <<= 1) {
        float4 o = (tid >= off) ? buf[tid - off] : make_float4(1.f, 1.f, 1.f, 1.f);
        __syncthreads();
        v = f4mul(v, o);
        buf[tid] = v;
        __syncthreads();
    }
    return v;
}

__global__ __launch_bounds__(256) void head_kernel(
    const unsigned short* __restrict__ H2, const float* __restrict__ W3,
    const float* __restrict__ b3, const int* __restrict__ nseg,
    float* __restrict__ out)
{
    __shared__ float4 buf[256];
    __shared__ float4 w3s[384];
    const int b = blockIdx.x, tid = threadIdx.x;
    for (int i = tid; i < 384; i += 256) w3s[i] = ((const float4*)W3)[i];
    __syncthreads();

    const unsigned short* hrow = H2 + (size_t)(b * 256 + tid) * 384;
    float4 acc = make_float4(b3[0], b3[1], b3[2], b3[3]);
    #pragma unroll
    for (int kk = 0; kk < 48; kk++) {
        ushort8 u = *(const ushort8*)(hrow + kk * 8);
        #pragma unroll
        for (int j = 0; j < 8; j++) {
            float h = bf2f(u[j]);
            float4 w = w3s[kk * 8 + j];
            acc.x += h * w.x; acc.y += h * w.y; acc.z += h * w.z; acc.w += h * w.w;
        }
    }
    float m = fmaxf(fmaxf(acc.x, acc.y), fmaxf(acc.z, acc.w));
    float e0 = __expf(acc.x - m), e1 = __expf(acc.y - m),
          e2 = __expf(acc.z - m), e3 = __expf(acc.w - m);
    float inv = 1.0f / (e0 + e1 + e2 + e3);
    float4 p = make_float4(e0 * inv, e1 * inv, e2 * inv, e3 * inv);

    const int n = nseg[b];
    const float4 ones = make_float4(1.f, 1.f, 1.f, 1.f);
    bool msk = tid < n;
    float s1 = p.x, s2 = s1 + p.y, s3 = s2 + p.z;
    float4 sm = msk ? make_float4(0.f, s1, s2, s3) : ones;

    scan_prod(sm, buf, tid);
    float4 pfx = (tid > 0) ? buf[tid - 1] : ones;
    __syncthreads();

    buf[255 - tid] = sm;
    __syncthreads();
    float4 rsm = buf[tid];
    scan_prod(rsm, buf, tid);
    float4 sfx = (tid < 255) ? buf[254 - tid] : ones;

    float4 L = f4mul(pfx, sfx);
    float4 cpL = scan_prod(L, buf, tid);

    float4 term = msk ? f4mul(p, cpL) : make_float4(0.f, 0.f, 0.f, 0.f);
    float4 pm = msk ? p : ones;

    __syncthreads();
    buf[tid] = term;
    __syncthreads();
    for (int off = 128; off > 0; off >>= 1) {
        if (tid < off) {
            float4 a = buf[tid], c = buf[tid + off];
            buf[tid] = make_float4(a.x + c.x, a.y + c.y, a.z + c.z, a.w + c.w);
        }
        __syncthreads();
    }
    float4 sum_t = buf[0];
    __syncthreads();

    buf[tid] = pm;
    __syncthreads();
    for (int off = 128; off > 0; off >>= 1) {
        if (tid < off) buf[tid] = f4mul(buf[tid], buf[tid + off]);
        __syncthreads();
    }
    if (tid == 0) {
        float4 pr = buf[0];
        ((float4*)out)[b] = make_float4(0.25f * sum_t.x + pr.x,
                                        0.25f * sum_t.y + pr.y,
                                        0.25f * sum_t.z + pr.z,
                                        0.25f * sum_t.w + pr.w);
    }
}

extern "C" void kernel_launch(void* const* d_in, const int* in_sizes, int n_in,
                              void* d_out, int out_size, void* d_ws, size_t ws_size,
                              hipStream_t stream) {
    (void)in_sizes; (void)n_in; (void)out_size; (void)ws_size;
    const float* questions = (const float*)d_in[0];
    const float* segments  = (const float*)d_in[1];
    const float* W1 = (const float*)d_in[2];
    const float* b1 = (const float*)d_in[3];
    const float* W2 = (const float*)d_in[4];
    const float* b2 = (const float*)d_in[5];
    const float* W3 = (const float*)d_in[6];
    const float* b3 = (const float*)d_in[7];
    const int*  nseg = (const int*)d_in[8];
    float* out = (float*)d_out;

    char* w = (char*)d_ws;
    float* qW1p = (float*)w;           w += (size_t)4 * 128 * 768 * 4;
    unsigned short* W1t = (unsigned short*)w; w += (size_t)768 * 768 * 2;
    unsigned short* W2t = (unsigned short*)w; w += (size_t)384 * 768 * 2;
    unsigned short* segB = (unsigned short*)w; w += (size_t)32768 * 768 * 2;
    unsigned short* H1b  = (unsigned short*)w; w += (size_t)32768 * 768 * 2;
    unsigned short* H2b  = (unsigned short*)w; w += (size_t)32768 * 384 * 2;

    prep_kernel<<<PREP_END, 256, 0, stream>>>(
        segments, segB, W1, W1t, W2, W2t, questions, qW1p);
    mfma_gemm_bt<<<dim3(6, 256), 256, 0, stream>>>(
        segB, W1t, b1, qW1p, H1b, 32768, 768, 768, 1);
    mfma_gemm_bt<<<dim3(3, 256), 256, 0, stream>>>(
        H1b, W2t, b2, nullptr, H2b, 32768, 384, 768, 1);
    head_kernel<<<128, 256, 0, stream>>>(H2b, W3, b3, nseg, out);
}